// Round 16
// baseline (538.485 us; speedup 1.0000x reference)
//
#include <hip/hip_runtime.h>
#include <hip/hip_bf16.h>
#include <stdint.h>

#define KDIM 1024
#define NROW 4096
#define NCOL 4096
#define INFV 1e30f
#define INFBITS 0x7149F2CAu     // bits of 1e30f
#define BM 128
#define BK 32

#define SKROWS 4160             // skewed cost rows
#define NBLK32 130              // 32-step blocks (tj 0..4159)
#define NPAIR  65               // 64-row pairs
#define NWG    16

typedef __bf16 bf16x8 __attribute__((ext_vector_type(8)));
typedef float f32x4 __attribute__((ext_vector_type(4)));

#define CFENCE asm volatile("" ::: "memory")

__device__ __forceinline__ unsigned short f2bf(float f) {
    __hip_bfloat16 h = __float2bfloat16(f);
    return *reinterpret_cast<unsigned short*>(&h);
}

__device__ __forceinline__ void gll16(const void* gsrc, void* ldst) {
    __builtin_amdgcn_global_load_lds(
        (const __attribute__((address_space(1))) void*)gsrc,
        (__attribute__((address_space(3))) void*)ldst, 16, 0, 0);
}

// ---------------------------------------------------------------------------
// Kernel 1: row-normalize both trajectories, emit bf16
// ---------------------------------------------------------------------------
__global__ __launch_bounds__(256) void normalize_bf16(
    const float* __restrict__ t1, const float* __restrict__ t2,
    unsigned short* __restrict__ o1, unsigned short* __restrict__ o2)
{
    int b = blockIdx.x;
    int t = threadIdx.x;
    const float* src;
    unsigned short* dst;
    if (b < NROW) { src = t1 + (size_t)b * KDIM;          dst = o1 + (size_t)b * KDIM; }
    else          { src = t2 + (size_t)(b - NROW) * KDIM; dst = o2 + (size_t)(b - NROW) * KDIM; }

    float4 v = reinterpret_cast<const float4*>(src)[t];
    float ss = v.x * v.x + v.y * v.y + v.z * v.z + v.w * v.w;
    #pragma unroll
    for (int d = 32; d >= 1; d >>= 1) ss += __shfl_xor(ss, d, 64);

    __shared__ float wsum[4];
    int wave = t >> 6;
    if ((t & 63) == 0) wsum[wave] = ss;
    __syncthreads();
    float inv = 1.0f / (sqrtf(wsum[0] + wsum[1] + wsum[2] + wsum[3]) + 1e-8f);

    ushort4 o;
    o.x = f2bf(v.x * inv);
    o.y = f2bf(v.y * inv);
    o.z = f2bf(v.z * inv);
    o.w = f2bf(v.w * inv);
    reinterpret_cast<ushort4*>(dst)[t] = o;
}

// ---------------------------------------------------------------------------
// Kernel 2: skewed cost: skew[i + ((j>>2)&63)][j] = 1 - dot(t1n[i], t2n[j])
// ---------------------------------------------------------------------------
__global__ __launch_bounds__(256) void gemm_cost(
    const unsigned short* __restrict__ A,
    const unsigned short* __restrict__ B,
    unsigned short* __restrict__ Cs)    // skewed [SKROWS][4096]
{
    __shared__ __align__(16) unsigned short As[BM * BK];
    __shared__ __align__(16) unsigned short Bs[BM * BK];

    int t    = threadIdx.x;
    int lane = t & 63;
    int wave = t >> 6;
    int i0   = blockIdx.y * BM;
    int j0   = blockIdx.x * BM;

    f32x4 acc[4][4];
    f32x4 zero = {0.f, 0.f, 0.f, 0.f};
    #pragma unroll
    for (int m = 0; m < 4; ++m)
        #pragma unroll
        for (int n = 0; n < 4; ++n) acc[m][n] = zero;

    int frow = lane & 15;
    int fk   = (lane >> 4) * 8;
    int wr   = (wave >> 1) * 64;
    int wc   = (wave & 1) * 64;

    int srow = t >> 2;
    int scb  = (t & 3) * 8;

    uint4 ra0, ra1, rb0, rb1;
    {
        ra0 = *reinterpret_cast<const uint4*>(A + (size_t)(i0 + srow) * KDIM + scb);
        ra1 = *reinterpret_cast<const uint4*>(A + (size_t)(i0 + 64 + srow) * KDIM + scb);
        rb0 = *reinterpret_cast<const uint4*>(B + (size_t)(j0 + srow) * KDIM + scb);
        rb1 = *reinterpret_cast<const uint4*>(B + (size_t)(j0 + 64 + srow) * KDIM + scb);
    }

    for (int k0 = 0; k0 < KDIM; k0 += BK) {
        __syncthreads();
        *reinterpret_cast<uint4*>(As + (size_t)t * 8)         = ra0;
        *reinterpret_cast<uint4*>(As + (size_t)(256 + t) * 8) = ra1;
        *reinterpret_cast<uint4*>(Bs + (size_t)t * 8)         = rb0;
        *reinterpret_cast<uint4*>(Bs + (size_t)(256 + t) * 8) = rb1;
        __syncthreads();

        if (k0 + BK < KDIM) {
            int kn = k0 + BK;
            ra0 = *reinterpret_cast<const uint4*>(A + (size_t)(i0 + srow) * KDIM + kn + scb);
            ra1 = *reinterpret_cast<const uint4*>(A + (size_t)(i0 + 64 + srow) * KDIM + kn + scb);
            rb0 = *reinterpret_cast<const uint4*>(B + (size_t)(j0 + srow) * KDIM + kn + scb);
            rb1 = *reinterpret_cast<const uint4*>(B + (size_t)(j0 + 64 + srow) * KDIM + kn + scb);
        }

        bf16x8 af[4], bfr[4];
        #pragma unroll
        for (int m = 0; m < 4; ++m)
            af[m] = *reinterpret_cast<const bf16x8*>(As + (wr + m * 16 + frow) * BK + fk);
        #pragma unroll
        for (int n = 0; n < 4; ++n)
            bfr[n] = *reinterpret_cast<const bf16x8*>(Bs + (wc + n * 16 + frow) * BK + fk);

        #pragma unroll
        for (int m = 0; m < 4; ++m)
            #pragma unroll
            for (int n = 0; n < 4; ++n)
                acc[m][n] = __builtin_amdgcn_mfma_f32_16x16x32_bf16(af[m], bfr[n], acc[m][n], 0, 0, 0);
    }

    int crow = (lane >> 4) * 4;
    int ccol = lane & 15;
    #pragma unroll
    for (int n = 0; n < 4; ++n) {
        const int j  = j0 + wc + n * 16 + ccol;
        const int Lj = (j >> 2) & 63;
        #pragma unroll
        for (int m = 0; m < 4; ++m) {
            const int ibase = i0 + wr + m * 16 + crow;
            #pragma unroll
            for (int q = 0; q < 4; ++q)
                Cs[(size_t)(ibase + q + Lj) * NCOL + j] = f2bf(1.0f - acc[m][n][q]);
        }
    }
}

// ---------------------------------------------------------------------------
// ring_init: prefill dummy segment (index 15) read by WG 0: tag = row+1,
// value = +INF.
// ---------------------------------------------------------------------------
__global__ __launch_bounds__(256) void ring_init(unsigned long long* __restrict__ ring)
{
    int i = blockIdx.x * 256 + threadIdx.x;
    ring[(size_t)15 * NROW + i] =
        ((unsigned long long)INFBITS << 32) | (unsigned)(i + 1);
}

// ---------------------------------------------------------------------------
// Kernel 3: systolic DTW, 16 WGs x 1 wave, free-running, 64-row PAIRS.
// Per pair m (blocks 2m,2m+1): 32 gll (cost for pair m+1) + 1 asm tag-load
// (64 tags, pair m+1... loaded one pair early) + 1 relaxed-agent publish
// STORE (64 boundary rows via 64 lanes) = 34 VMEM ops -> one vmcnt(34)
// binding rv0 (forces exactly R(m)+G(2m,2m+1); the publish store ages ~1.8
// pairs before any wait forces it). 4-slot LDS cost ring, slot keyed on the
// UNCLAMPED block id (fixes R14's tail-block overwrite race).
// ---------------------------------------------------------------------------
__global__ __launch_bounds__(64, 1) void dtw_systolic(
    const unsigned short* __restrict__ cost,   // skewed [SKROWS][4096]
    unsigned long long* __restrict__ ring,     // [16][4096] + garb[16][64]
    float* __restrict__ out)
{
    __shared__ __align__(16) unsigned char clds[4 * 16384];  // 4-slot cost ring
    __shared__ float outT[128];    // lane63 row-values, 128-row ring
    __shared__ float outD[64];     // per-lane dump (conflict-free)

    const int w    = blockIdx.x;
    const int lane = threadIdx.x;
    const char* skewb = (const char*)cost;
    const unsigned long long* rseg = ring + (size_t)((w == 0) ? 15 : (w - 1)) * NROW;
    unsigned long long* wseg = ring + (size_t)w * NROW;        // unused for w=15
    unsigned long long* garb = ring + (size_t)NWG * NROW + w * 64;
    const unsigned stripeByte = (unsigned)w * 512u + ((unsigned)(lane & 31) << 4);

    float pd0 = INFV, pd1 = INFV, pd2 = INFV, pd3 = INFV;
    float lprev = (w == 0 && lane == 0) ? 0.0f : INFV;   // DP origin seed
    float d3p = INFV;
    unsigned ansb = INFBITS;
    unsigned long long rv0 = 0;

// stage 32 rows of block STG into slot (STG&3); rows clamped, slot NOT
#define GLL16S(STG) { const int stg_ = (STG); \
    unsigned char* ldsb_ = clds + (stg_ & 3) * 16384; \
    _Pragma("unroll") \
    for (int g_ = 0; g_ < 16; ++g_) { \
        int sr_ = 32 * stg_ + 2 * g_ + (lane >> 5); \
        if (sr_ > SKROWS - 1) sr_ = SKROWS - 1; \
        gll16(skewb + (size_t)sr_ * 8192 + stripeByte, ldsb_ + g_ * 1024); } }

// asm 64-tag load for pair-group PG (rows 64*PG + lane), clamped
#define RINGLD(DST, PG) { int pg_ = (PG); pg_ = pg_ < 0 ? 0 : (pg_ > 63 ? 63 : pg_); \
    const unsigned off_ = (64u * (unsigned)pg_ + (unsigned)lane) * 8u; \
    asm volatile("global_load_dwordx2 %0, %1, %2 sc0 sc1" \
                 : "=v"(DST) : "v"(off_), "s"(rseg) : "memory"); }

#define DCOMP(K, CU, RL) { \
    const unsigned rbK = (unsigned)__builtin_amdgcn_readlane(rvhi, (RL)); \
    const float lcur = __uint_as_float((unsigned)__builtin_amdgcn_update_dpp( \
        (int)rbK, (int)__float_as_uint(d3p), 0x138, 0xf, 0xf, false)); \
    const float c0 = __uint_as_float(CU.x << 16); \
    const float c1 = __uint_as_float(CU.x & 0xffff0000u); \
    const float c2 = __uint_as_float(CU.y << 16); \
    const float c3 = __uint_as_float(CU.y & 0xffff0000u); \
    const float n0 = c0 + fminf(pd0, lprev); \
    const float n1 = c1 + fminf(pd1, pd0); \
    const float n2 = c2 + fminf(pd2, pd1); \
    const float n3 = c3 + fminf(pd3, pd2); \
    const float e0 = fminf(lcur + c0, n0); \
    const float e1 = fminf(e0 + c1, n1); \
    const float e2 = fminf(e1 + c2, n2); \
    const float e3 = fminf(e2 + c3, n3); \
    float* sp_ = (lane == 63) ? &outT[(unsigned)(rowbase + (K)) & 127u] \
                              : &outD[lane]; \
    *sp_ = e3; \
    ansb = (tjb + (K) == 4158) ? __float_as_uint(e3) : ansb; \
    lprev = lcur; d3p = e3; \
    pd0 = e0; pd1 = e1; pd2 = e2; pd3 = e3; }

#define BLOCK32(SLOT, RB, TJ, RLOFF) { \
    const uint2* lu = reinterpret_cast<const uint2*>( \
        clds + (SLOT) * 16384 + (lane << 3)); \
    const int rowbase = (RB); const int tjb = (TJ); \
    const uint2 cc0  = lu[0 * 64],  cc1  = lu[1 * 64]; \
    const uint2 cc2  = lu[2 * 64],  cc3  = lu[3 * 64]; \
    const uint2 cc4  = lu[4 * 64],  cc5  = lu[5 * 64]; \
    const uint2 cc6  = lu[6 * 64],  cc7  = lu[7 * 64]; \
    const uint2 cc8  = lu[8 * 64],  cc9  = lu[9 * 64]; \
    const uint2 cc10 = lu[10 * 64], cc11 = lu[11 * 64]; \
    const uint2 cc12 = lu[12 * 64], cc13 = lu[13 * 64]; \
    const uint2 cc14 = lu[14 * 64], cc15 = lu[15 * 64]; \
    const uint2 cc16 = lu[16 * 64], cc17 = lu[17 * 64]; \
    const uint2 cc18 = lu[18 * 64], cc19 = lu[19 * 64]; \
    const uint2 cc20 = lu[20 * 64], cc21 = lu[21 * 64]; \
    const uint2 cc22 = lu[22 * 64], cc23 = lu[23 * 64]; \
    const uint2 cc24 = lu[24 * 64], cc25 = lu[25 * 64]; \
    const uint2 cc26 = lu[26 * 64], cc27 = lu[27 * 64]; \
    const uint2 cc28 = lu[28 * 64], cc29 = lu[29 * 64]; \
    const uint2 cc30 = lu[30 * 64], cc31 = lu[31 * 64]; \
    DCOMP(0,  cc0,  (RLOFF)+0)  DCOMP(1,  cc1,  (RLOFF)+1) \
    DCOMP(2,  cc2,  (RLOFF)+2)  DCOMP(3,  cc3,  (RLOFF)+3) \
    DCOMP(4,  cc4,  (RLOFF)+4)  DCOMP(5,  cc5,  (RLOFF)+5) \
    DCOMP(6,  cc6,  (RLOFF)+6)  DCOMP(7,  cc7,  (RLOFF)+7) \
    DCOMP(8,  cc8,  (RLOFF)+8)  DCOMP(9,  cc9,  (RLOFF)+9) \
    DCOMP(10, cc10, (RLOFF)+10) DCOMP(11, cc11, (RLOFF)+11) \
    DCOMP(12, cc12, (RLOFF)+12) DCOMP(13, cc13, (RLOFF)+13) \
    DCOMP(14, cc14, (RLOFF)+14) DCOMP(15, cc15, (RLOFF)+15) \
    DCOMP(16, cc16, (RLOFF)+16) DCOMP(17, cc17, (RLOFF)+17) \
    DCOMP(18, cc18, (RLOFF)+18) DCOMP(19, cc19, (RLOFF)+19) \
    DCOMP(20, cc20, (RLOFF)+20) DCOMP(21, cc21, (RLOFF)+21) \
    DCOMP(22, cc22, (RLOFF)+22) DCOMP(23, cc23, (RLOFF)+23) \
    DCOMP(24, cc24, (RLOFF)+24) DCOMP(25, cc25, (RLOFF)+25) \
    DCOMP(26, cc26, (RLOFF)+26) DCOMP(27, cc27, (RLOFF)+27) \
    DCOMP(28, cc28, (RLOFF)+28) DCOMP(29, cc29, (RLOFF)+29) \
    DCOMP(30, cc30, (RLOFF)+30) DCOMP(31, cc31, (RLOFF)+31) }

    // prologue: [G(0)x16, G(1)x16, R(0), dummy ST] = 34 ops (uniform count)
    GLL16S(0) GLL16S(1)
    RINGLD(rv0, 0)
    __hip_atomic_store(garb + lane, 0ull, __ATOMIC_RELAXED, __HIP_MEMORY_SCOPE_AGENT);
    CFENCE;

    #pragma unroll 1
    for (int m = 0; m < NPAIR; ++m) {
        // prefetch next pair's cost blocks + tags (33 ops)
        GLL16S(2 * m + 2) GLL16S(2 * m + 3)
        unsigned long long rvN;
        RINGLD(rvN, m + 1)
        CFENCE;
        // forces R(m) + G(2m) + G(2m+1); publish stores age ~1.8 pairs
        asm volatile("s_waitcnt vmcnt(34)" : "+v"(rv0) :: "memory");

        // tag check: group m = rows 64m..64m+63 (all 64 lanes)
        if (m < 64) {
            const unsigned expt = 64u * (unsigned)m + (unsigned)lane + 1u;
            while (__ballot((unsigned)rv0 == expt) != ~0ull)
                rv0 = __hip_atomic_load(rseg + 64u * (unsigned)m + (unsigned)lane,
                                        __ATOMIC_RELAXED, __HIP_MEMORY_SCOPE_AGENT);
        }
        const int rvhi = (int)(unsigned)(rv0 >> 32);

        // compute blocks 2m and 2m+1
        BLOCK32((2 * m) & 3,     64 * m - 63,      64 * m,      0)
        BLOCK32((2 * m + 1) & 3, 64 * m + 32 - 63, 64 * m + 32, 32)

        // publish group m-1 (rows 64(m-1)..64(m-1)+63) via relaxed agent
        // store (1 instruction, 64 lanes); garb when invalid -> uniform count
        {
            const int r = 64 * (m - 1) + lane;
            const float bv = outT[(unsigned)r & 127u];
            const bool valid = (m >= 1) && (w < NWG - 1);
            const unsigned long long pk =
                ((unsigned long long)__float_as_uint(bv) << 32) | (unsigned)(r + 1);
            unsigned long long* sp = valid ? (wseg + r) : (garb + lane);
            __hip_atomic_store(sp, pk, __ATOMIC_RELAXED, __HIP_MEMORY_SCOPE_AGENT);
        }
        CFENCE;

        rv0 = rvN;
    }

#undef GLL16S
#undef RINGLD
#undef DCOMP
#undef BLOCK32

    if (w == NWG - 1 && lane == 63) out[0] = 1.0f / (1.0f + __uint_as_float(ansb));
}

// ---------------------------------------------------------------------------
extern "C" void kernel_launch(void* const* d_in, const int* in_sizes, int n_in,
                              void* d_out, int out_size, void* d_ws, size_t ws_size,
                              hipStream_t stream)
{
    const float* t1 = (const float*)d_in[0];
    const float* t2 = (const float*)d_in[1];
    float* out = (float*)d_out;

    char* ws = (char*)d_ws;
    unsigned short* t1n  = (unsigned short*)ws;                                   // 8 MB
    unsigned short* t2n  = (unsigned short*)(ws + (size_t)NROW * KDIM * 2);       // 8 MB
    unsigned short* skew = (unsigned short*)(ws + (size_t)16 * 1024 * 1024);      // 34.1 MB
    unsigned long long* ring = (unsigned long long*)(ws + (size_t)52 * 1024 * 1024);
    // ring: segs 0..14 real interfaces, seg 15 = dummy-INF for WG0,
    // then 16x64 garb slots (~520 KB total)

    hipMemsetAsync(ring, 0, (size_t)15 * NROW * 8, stream);
    ring_init<<<NROW / 256, 256, 0, stream>>>(ring);
    normalize_bf16<<<2 * NROW, 256, 0, stream>>>(t1, t2, t1n, t2n);
    gemm_cost<<<dim3(NCOL / BM, NROW / BM), 256, 0, stream>>>(t1n, t2n, skew);
    dtw_systolic<<<NWG, 64, 0, stream>>>(skew, ring, out);
}